// Round 15
// baseline (662.764 us; speedup 1.0000x reference)
//
#include <hip/hip_runtime.h>

typedef unsigned short u16;
typedef float f32x16 __attribute__((ext_vector_type(16)));
typedef short bf16x8 __attribute__((ext_vector_type(8)));
typedef unsigned short u16x8 __attribute__((ext_vector_type(8)));

#define ND 768
#define KD 768

__device__ __forceinline__ float bf2f(u16 u) {
    union { unsigned i; float f; } v; v.i = ((unsigned)u) << 16; return v.f;
}
__device__ __forceinline__ u16 f2bf(float f) {
    union { float f; unsigned u; } x; x.f = f;
    unsigned r = x.u + 0x7fffu + ((x.u >> 16) & 1u);
    return (u16)(r >> 16);
}
__device__ __forceinline__ void async16(const void* g, void* l) {
    __builtin_amdgcn_global_load_lds((const __attribute__((address_space(1))) void*)g,
                                     (__attribute__((address_space(3))) void*)l, 16, 0, 0);
}

// ---- fused prep: 3 weight transposes + We/W3 bf16 casts + w3ai/w3aj/bfus ----
// blocks 0..431:    conv_w for m in {1,2,4} (W1, W2, W_out -> Wt K-major bf16)
// blocks 432..1583: row-major bf16 casts of We (576) and W3 (576)
// blocks 1584..1775: wave-per-d vecs: w3ai/w3aj (W3 rows), bfus (W1 cols + f2bf)
__global__ __launch_bounds__(256) void mega_prep(const float* __restrict__ W_emb,
                                                 const float* __restrict__ gat_W,
                                                 const float* __restrict__ W_out,
                                                 const float* __restrict__ gat_a,
                                                 const float* __restrict__ be,
                                                 u16* __restrict__ Wt,
                                                 u16* __restrict__ WeBf,
                                                 u16* __restrict__ W3Bf,
                                                 float* __restrict__ w3ai,
                                                 float* __restrict__ w3aj,
                                                 float* __restrict__ bfus)
{
    __shared__ float lds[64][65];
    const int blk = blockIdx.x;
    const int tid = threadIdx.x;
    if (blk < 432) {
        const int mi = blk / 144;                 // 0,1,2
        const int mm = (mi == 0) ? 1 : (mi == 1) ? 2 : 4;
        const float* src = (mm == 4) ? W_out : gat_W + (size_t)(mm - 1) * 589824;
        const int r  = blk % 144;
        const int tr = r / 12, tc = r % 12;
        const int c  = tid & 63, w4 = tid >> 6;
        #pragma unroll
        for (int i = 0; i < 16; ++i) {
            int kk = i * 4 + w4;
            lds[kk][c] = src[(size_t)(tr * 64 + kk) * 768 + tc * 64 + c];
        }
        __syncthreads();
        u16* dst = Wt + (size_t)mm * 589824;
        #pragma unroll
        for (int i = 0; i < 16; ++i) {
            int nn = i * 4 + w4;
            dst[(size_t)(tc * 64 + nn) * 768 + tr * 64 + c] = f2bf(lds[c][nn]);
        }
    } else if (blk < 1584) {
        int bi = blk - 432;
        const float4* src;
        u16* dst;
        if (bi < 576) { src = (const float4*)W_emb; dst = WeBf; }
        else          { src = (const float4*)(gat_W + 2 * 589824); dst = W3Bf; bi -= 576; }
        const int i = bi * 256 + tid;             // < 147456
        float4 v = src[i];
        union { u16 s[4]; uint2 u; } o;
        o.s[0] = f2bf(v.x); o.s[1] = f2bf(v.y); o.s[2] = f2bf(v.z); o.s[3] = f2bf(v.w);
        ((uint2*)dst)[i] = o.u;
    } else {
        const int lane = tid & 63;
        const int d = (blk - 1584) * 4 + (tid >> 6);   // < 768
        const float* w3row = gat_W + 2 * 589824 + (size_t)d * 768;
        const float* ga2   = gat_a + 2 * 1536;
        const float* W1    = gat_W;                    // layer 0 weights
        float ai = 0.f, aj = 0.f, bf = 0.f;
        for (int j = lane; j < 768; j += 64) {
            float w = w3row[j];
            ai += w * ga2[j];
            aj += w * ga2[768 + j];
            bf += be[j] * bf2f(f2bf(W1[(size_t)j * 768 + d]));
        }
        #pragma unroll
        for (int off = 32; off; off >>= 1) {
            ai += __shfl_down(ai, off);
            aj += __shfl_down(aj, off);
            bf += __shfl_down(bf, off);
        }
        if (lane == 0) { w3ai[d] = ai; w3aj[d] = aj; bfus[d] = bf; }
    }
}

// ---- bf16 GEMM: depth-2 prefetch, 3-buffer circular LDS, counted vmcnt(4) ----
// A2/Bt2: second operand pair selected when tm>=768 (stacked prep GEMM).
template<bool F32OUT, bool SWZ>
__global__ __launch_bounds__(256) void gemm_bt(const u16* __restrict__ A,
                                               const u16* __restrict__ A2,
                                               const u16* __restrict__ Bt,
                                               const u16* __restrict__ Bt2,
                                               const float* __restrict__ bias,
                                               void* __restrict__ Cout)
{
    __shared__ u16 lds3[3][2][4096];   // 48 KB: 3 slots x (A | B) x 128r x 32
    const int tid  = threadIdx.x;
    const int lane = tid & 63;
    const int wvb  = tid & ~63;
    const int wm   = ((tid >> 7) & 1) * 64;
    const int wn   = ((tid >> 6) & 1) * 64;
    const int wg = blockIdx.x;
    const int id = SWZ ? ((wg & 7) * 336 + (wg >> 3)) : wg;
    const int tn = (id % 6) * 128;
    const int tm = (id / 6) * 128;
    const bool hi = (A2 != nullptr) && (tm >= 768);
    const u16* AU  = hi ? A2 : A;
    const u16* BtU = hi ? Bt2 : Bt;
    const int tmA  = hi ? tm - 768 : tm;

    f32x16 acc[2][2] = {};

    const int r31 = lane & 31;
    const int l5  = lane >> 5;
    const int key = (r31 >> 1) & 3;

    const int row0 = tid >> 2;
    const int kc0  = (((tid & 3) ^ ((tid >> 3) & 3)) << 3);
    const u16* aSrc = AU  + (size_t)(tmA + row0) * KD + kc0;
    const u16* bSrc = BtU + (size_t)(tn + row0) * KD + kc0;

    #define STAGE(b, ks_) { const int k0 = (ks_) * 32;                       \
        async16(aSrc + k0,                   &lds3[b][0][wvb * 8]);          \
        async16(aSrc + (size_t)64 * KD + k0, &lds3[b][0][(256 + wvb) * 8]);  \
        async16(bSrc + k0,                   &lds3[b][1][wvb * 8]);          \
        async16(bSrc + (size_t)64 * KD + k0, &lds3[b][1][(256 + wvb) * 8]); }

    STAGE(0, 0);
    STAGE(1, 1);

    #pragma unroll 3
    for (int ks = 0; ks < KD / 32; ++ks) {
        const int cur = ks % 3;
        if (ks < KD / 32 - 1)
            asm volatile("s_waitcnt vmcnt(4)" ::: "memory");
        else
            asm volatile("s_waitcnt vmcnt(0)" ::: "memory");
        __builtin_amdgcn_s_barrier();
        asm volatile("" ::: "memory");
        if (ks + 2 < KD / 32) STAGE((ks + 2) % 3, ks + 2);

        const u16* As = lds3[cur][0];
        const u16* Bs = lds3[cur][1];
        bf16x8 af[2][2], bf[2][2];
        #pragma unroll
        for (int fr = 0; fr < 2; ++fr)
            #pragma unroll
            for (int ka = 0; ka < 2; ++ka) {
                int chA = ((ka * 2 + l5) ^ key) << 3;
                af[fr][ka] = *(const bf16x8*)&As[(wm + fr * 32 + r31) * 32 + chA];
                bf[fr][ka] = *(const bf16x8*)&Bs[(wn + fr * 32 + r31) * 32 + chA];
            }
        #pragma unroll
        for (int fr = 0; fr < 2; ++fr)
            #pragma unroll
            for (int fc = 0; fc < 2; ++fc)
                #pragma unroll
                for (int ka = 0; ka < 2; ++ka)
                    acc[fr][fc] = __builtin_amdgcn_mfma_f32_32x32x16_bf16(
                        af[fr][ka], bf[fc][ka], acc[fr][fc], 0, 0, 0);
    }
    #undef STAGE

    #pragma unroll
    for (int fc = 0; fc < 2; ++fc) {
        int col = tn + wn + fc * 32 + r31;
        float bv = bias ? bias[col] : 0.0f;
        #pragma unroll
        for (int fr = 0; fr < 2; ++fr) {
            int rowb = tm + wm + fr * 32 + 4 * l5;
            #pragma unroll
            for (int reg = 0; reg < 16; ++reg) {
                int row = rowb + (reg & 3) + 8 * (reg >> 2);
                float v = acc[fr][fc][reg] + bv;
                if (F32OUT)
                    ((float*)Cout)[(size_t)row * ND + col] = v;
                else
                    ((u16*)Cout)[(size_t)row * ND + col] = f2bf(v);
            }
        }
    }
}

// ---- L0 GEMM: fp32 A direct via global_load_lds (no pre-cast), bf16 B ----
// A staged fp32 into LDS (16KB/slot, chunk-swizzle p = c ^ (row&7)); converted
// to bf16 at fragment-read time (identical rounding chain to pre-cast path).
// 3 slots: LDS 72KB -> 2 blocks/CU. 6 loads/STAGE -> counted vmcnt(6).
template<bool SWZ>
__global__ __launch_bounds__(256) void gemm_a32(const float* __restrict__ A,
                                                const u16* __restrict__ Bt,
                                                const float* __restrict__ bias,
                                                u16* __restrict__ Cout)
{
    __shared__ float ldsA[3][4096];    // 48 KB: fp32 A, 16B-chunk swizzled
    __shared__ u16   ldsB[3][4096];    // 24 KB: bf16 B (verified layout)
    const int tid  = threadIdx.x;
    const int lane = tid & 63;
    const int wvb  = tid & ~63;
    const int wm   = ((tid >> 7) & 1) * 64;
    const int wn   = ((tid >> 6) & 1) * 64;
    const int wg = blockIdx.x;
    const int id = SWZ ? ((wg & 7) * 336 + (wg >> 3)) : wg;
    const int tn = (id % 6) * 128;
    const int tm = (id / 6) * 128;

    f32x16 acc[2][2] = {};

    const int r31 = lane & 31;
    const int l5  = lane >> 5;
    const int key = (r31 >> 1) & 3;    // B swizzle key
    const int k7  = r31 & 7;           // A swizzle key

    // B staging (bf16, 2 chunks/thread)
    const int row0 = tid >> 2;
    const int kc0  = (((tid & 3) ^ ((tid >> 3) & 3)) << 3);
    const u16* bSrc = Bt + (size_t)(tn + row0) * KD + kc0;
    // A staging (fp32, 4 chunks/thread): chunk c: row=c>>3, phys p=c&7,
    // global slot s = p ^ (row&7)
    const float* aS0; const float* aS1; const float* aS2; const float* aS3;
    {
        int c0 = tid, c1 = 256 + tid, c2 = 512 + tid, c3 = 768 + tid;
        aS0 = A + (size_t)(tm + (c0 >> 3)) * KD + (((c0 & 7) ^ ((c0 >> 3) & 7)) << 2);
        aS1 = A + (size_t)(tm + (c1 >> 3)) * KD + (((c1 & 7) ^ ((c1 >> 3) & 7)) << 2);
        aS2 = A + (size_t)(tm + (c2 >> 3)) * KD + (((c2 & 7) ^ ((c2 >> 3) & 7)) << 2);
        aS3 = A + (size_t)(tm + (c3 >> 3)) * KD + (((c3 & 7) ^ ((c3 >> 3) & 7)) << 2);
    }

    #define STAGE(b, ks_) { const int k0 = (ks_) * 32;                        \
        async16(aS0 + k0, &((u16*)ldsA[b])[(wvb) * 8]);                       \
        async16(aS1 + k0, &((u16*)ldsA[b])[(256 + wvb) * 8]);                 \
        async16(aS2 + k0, &((u16*)ldsA[b])[(512 + wvb) * 8]);                 \
        async16(aS3 + k0, &((u16*)ldsA[b])[(768 + wvb) * 8]);                 \
        async16(bSrc + k0,                   &ldsB[b][wvb * 8]);              \
        async16(bSrc + (size_t)64 * KD + k0, &ldsB[b][(256 + wvb) * 8]); }

    STAGE(0, 0);
    STAGE(1, 1);

    #pragma unroll 3
    for (int ks = 0; ks < KD / 32; ++ks) {
        const int cur = ks % 3;
        if (ks < KD / 32 - 1)
            asm volatile("s_waitcnt vmcnt(6)" ::: "memory");
        else
            asm volatile("s_waitcnt vmcnt(0)" ::: "memory");
        __builtin_amdgcn_s_barrier();
        asm volatile("" ::: "memory");
        if (ks + 2 < KD / 32) STAGE((ks + 2) % 3, ks + 2);

        const float* As = ldsA[cur];
        const u16*   Bs = ldsB[cur];
        bf16x8 af[2][2], bf[2][2];
        #pragma unroll
        for (int fr = 0; fr < 2; ++fr)
            #pragma unroll
            for (int ka = 0; ka < 2; ++ka) {
                const int rA = (wm + fr * 32 + r31) * 32;   // row base (floats)
                const int l0 = (ka * 2 + l5) * 2;           // logical 16B chunk
                float4 f0 = *(const float4*)&As[rA + ((l0 ^ k7) << 2)];
                float4 f1 = *(const float4*)&As[rA + (((l0 + 1) ^ k7) << 2)];
                union { u16 s[8]; bf16x8 v; } pk;
                pk.s[0] = f2bf(f0.x); pk.s[1] = f2bf(f0.y);
                pk.s[2] = f2bf(f0.z); pk.s[3] = f2bf(f0.w);
                pk.s[4] = f2bf(f1.x); pk.s[5] = f2bf(f1.y);
                pk.s[6] = f2bf(f1.z); pk.s[7] = f2bf(f1.w);
                af[fr][ka] = pk.v;
                int chB = ((ka * 2 + l5) ^ key) << 3;
                bf[fr][ka] = *(const bf16x8*)&Bs[(wn + fr * 32 + r31) * 32 + chB];
            }
        #pragma unroll
        for (int fr = 0; fr < 2; ++fr)
            #pragma unroll
            for (int fc = 0; fc < 2; ++fc)
                #pragma unroll
                for (int ka = 0; ka < 2; ++ka)
                    acc[fr][fc] = __builtin_amdgcn_mfma_f32_32x32x16_bf16(
                        af[fr][ka], bf[fc][ka], acc[fr][fc], 0, 0, 0);
    }
    #undef STAGE

    #pragma unroll
    for (int fc = 0; fc < 2; ++fc) {
        int col = tn + wn + fc * 32 + r31;
        float bv = bias ? bias[col] : 0.0f;
        #pragma unroll
        for (int fr = 0; fr < 2; ++fr) {
            int rowb = tm + wm + fr * 32 + 4 * l5;
            #pragma unroll
            for (int reg = 0; reg < 16; ++reg) {
                int row = rowb + (reg & 3) + 8 * (reg >> 2);
                Cout[(size_t)row * ND + col] = f2bf(acc[fr][fc][reg] + bv);
            }
        }
    }
}

// ---- fused GAT attention: ei/ej from staged Wh, softmax, mix, ELU ----
template<bool ELU, bool DOTS>
__global__ __launch_bounds__(256) void gat_mix(const u16* __restrict__ Wh,
                                               const float* __restrict__ adj,
                                               const float* __restrict__ avec,
                                               float* __restrict__ attn_out,
                                               u16* __restrict__ Xout,
                                               const float* __restrict__ w3ai,
                                               const float* __restrict__ w3aj,
                                               float* __restrict__ eiOut,
                                               float* __restrict__ ejOut)
{
    __shared__ u16 wh[14 * 768];
    __shared__ float s_ei[14], s_ej[14];
    __shared__ float s_attn[196];
    __shared__ float s_dots[14][2];
    const int b = blockIdx.x;
    const int tid = threadIdx.x;
    const u16* whb = Wh + (size_t)b * 10752;

    if (DOTS && tid < 28) ((float*)s_dots)[tid] = 0.f;
    for (int c = tid; c < 1344; c += 256)
        ((uint4*)wh)[c] = ((const uint4*)whb)[c];
    __syncthreads();

    if (tid < 224) {
        const int i = tid >> 4, l = tid & 15;
        float ai = 0.f, aj = 0.f;
        #pragma unroll
        for (int c = 0; c < 6; ++c) {
            int d = c * 128 + l * 8;
            u16x8 v  = *(const u16x8*)&wh[i * 768 + d];
            float4 x0 = *(const float4*)&avec[d];
            float4 x1 = *(const float4*)&avec[d + 4];
            float4 y0 = *(const float4*)&avec[768 + d];
            float4 y1 = *(const float4*)&avec[768 + d + 4];
            float w0 = bf2f(v[0]), w1 = bf2f(v[1]), w2 = bf2f(v[2]), w3 = bf2f(v[3]);
            float w4 = bf2f(v[4]), w5 = bf2f(v[5]), w6 = bf2f(v[6]), w7 = bf2f(v[7]);
            ai += w0*x0.x + w1*x0.y + w2*x0.z + w3*x0.w + w4*x1.x + w5*x1.y + w6*x1.z + w7*x1.w;
            aj += w0*y0.x + w1*y0.y + w2*y0.z + w3*y0.w + w4*y1.x + w5*y1.y + w6*y1.z + w7*y1.w;
        }
        #pragma unroll
        for (int off = 8; off; off >>= 1) {
            ai += __shfl_xor(ai, off);
            aj += __shfl_xor(aj, off);
        }
        if (l == 0) { s_ei[i] = ai; s_ej[i] = aj; }
    }
    __syncthreads();

    if (tid < 14) {
        const int i = tid;
        float e[14];
        float mx = -3.0e38f;
        #pragma unroll
        for (int j = 0; j < 14; ++j) {
            float ev = (adj[(size_t)b * 196 + i * 14 + j] > 0.f) ? (s_ei[i] + s_ej[j]) : -1.0e30f;
            e[j] = ev; mx = fmaxf(mx, ev);
        }
        float sum = 0.f;
        #pragma unroll
        for (int j = 0; j < 14; ++j) { float pp = __expf(e[j] - mx); e[j] = pp; sum += pp; }
        float inv = 1.0f / sum;
        #pragma unroll
        for (int j = 0; j < 14; ++j) s_attn[i * 14 + j] = e[j] * inv;
    }
    __syncthreads();

    if (tid < 196) attn_out[(size_t)b * 196 + tid] = s_attn[tid];

    for (int pp = tid; pp < 14 * 48; pp += 256) {
        const int i  = pp / 48;
        const int d0 = (pp % 48) * 16;
        float acc[16] = {};
        #pragma unroll
        for (int j = 0; j < 14; ++j) {
            float aw = s_attn[i * 14 + j];
            u16x8 wv0 = *(const u16x8*)&wh[j * 768 + d0];
            u16x8 wv1 = *(const u16x8*)&wh[j * 768 + d0 + 8];
            #pragma unroll
            for (int qq = 0; qq < 8; ++qq) {
                acc[qq]     += aw * bf2f(wv0[qq]);
                acc[8 + qq] += aw * bf2f(wv1[qq]);
            }
        }
        float pi = 0.f, pj = 0.f;
        union { u16 s[16]; uint4 u[2]; } o;
        #pragma unroll
        for (int qq = 0; qq < 16; ++qq) {
            float v = acc[qq];
            if (ELU && v < 0.f) v = __expf(v) - 1.0f;
            if (DOTS) { pi += v * w3ai[d0 + qq]; pj += v * w3aj[d0 + qq]; }
            o.s[qq] = f2bf(v);
        }
        if (DOTS) {
            atomicAdd(&s_dots[i][0], pi);
            atomicAdd(&s_dots[i][1], pj);
        }
        *(uint4*)&Xout[(size_t)b * 10752 + i * 768 + d0]     = o.u[0];
        *(uint4*)&Xout[(size_t)b * 10752 + i * 768 + d0 + 8] = o.u[1];
    }
    if (DOTS) {
        __syncthreads();
        if (tid < 14) {
            eiOut[(size_t)b * 14 + tid] = s_dots[tid][0];
            ejOut[(size_t)b * 14 + tid] = s_dots[tid][1];
        }
    }
}

// ---- final layer: softmax from precomputed ei3/ej3, out = attn2 @ Z + b_out ----
__global__ __launch_bounds__(256) void gat_out(const u16* __restrict__ Z,
                                               const float* __restrict__ adj,
                                               const float* __restrict__ eiG,
                                               const float* __restrict__ ejG,
                                               const float* __restrict__ b_out,
                                               float* __restrict__ attn_out,
                                               float* __restrict__ outp)
{
    __shared__ u16 wh[14 * 768];
    __shared__ float s_attn[196];
    const int b = blockIdx.x;
    const int tid = threadIdx.x;
    const u16* zb = Z + (size_t)b * 10752;

    for (int c = tid; c < 1344; c += 256)
        ((uint4*)wh)[c] = ((const uint4*)zb)[c];

    if (tid < 14) {
        const int i = tid;
        float ei = eiG[(size_t)b * 14 + i];
        float e[14];
        float mx = -3.0e38f;
        #pragma unroll
        for (int j = 0; j < 14; ++j) {
            float ev = (adj[(size_t)b * 196 + i * 14 + j] > 0.f)
                           ? (ei + ejG[(size_t)b * 14 + j]) : -1.0e30f;
            e[j] = ev; mx = fmaxf(mx, ev);
        }
        float sum = 0.f;
        #pragma unroll
        for (int j = 0; j < 14; ++j) { float pp = __expf(e[j] - mx); e[j] = pp; sum += pp; }
        float inv = 1.0f / sum;
        #pragma unroll
        for (int j = 0; j < 14; ++j) s_attn[i * 14 + j] = e[j] * inv;
    }
    __syncthreads();

    if (tid < 196) attn_out[(size_t)b * 196 + tid] = s_attn[tid];

    for (int pp = tid; pp < 14 * 48; pp += 256) {
        const int i  = pp / 48;
        const int d0 = (pp % 48) * 16;
        float acc[16];
        #pragma unroll
        for (int qq = 0; qq < 16; ++qq) acc[qq] = b_out[d0 + qq];
        #pragma unroll
        for (int j = 0; j < 14; ++j) {
            float aw = s_attn[i * 14 + j];
            u16x8 wv0 = *(const u16x8*)&wh[j * 768 + d0];
            u16x8 wv1 = *(const u16x8*)&wh[j * 768 + d0 + 8];
            #pragma unroll
            for (int qq = 0; qq < 8; ++qq) {
                acc[qq]     += aw * bf2f(wv0[qq]);
                acc[8 + qq] += aw * bf2f(wv1[qq]);
            }
        }
        float* dst = &outp[(size_t)b * 10752 + i * 768 + d0];
        *(float4*)(dst)      = *(float4*)&acc[0];
        *(float4*)(dst + 4)  = *(float4*)&acc[4];
        *(float4*)(dst + 8)  = *(float4*)&acc[8];
        *(float4*)(dst + 12) = *(float4*)&acc[12];
    }
}

extern "C" void kernel_launch(void* const* d_in, const int* in_sizes, int n_in,
                              void* d_out, int out_size, void* d_ws, size_t ws_size,
                              hipStream_t stream)
{
    const float* features = (const float*)d_in[0];
    const float* adj      = (const float*)d_in[1];
    const float* W_emb    = (const float*)d_in[2];
    const float* b_emb    = (const float*)d_in[3];
    const float* gat_W    = (const float*)d_in[4];
    const float* gat_a    = (const float*)d_in[5];
    const float* W_out    = (const float*)d_in[6];
    const float* b_out    = (const float*)d_in[7];
    float* out = (float*)d_out;

    // ws: Wh (bf16 57344x768) | Wt[7] | w3ai | w3aj | bfus | eiG | ejG
    u16* Wh = (u16*)d_ws;
    u16* Wt = Wh + 44040192;
    float* w3ai = (float*)(Wt + 7 * 589824);
    float* w3aj = w3ai + 768;
    float* bfus = w3aj + 768;
    float* eiG  = bfus + 768;
    float* ejG  = eiG + 57344;
    // out-region: ping-pong bf16 halves; WeW3 staging aliases H1 (dead by mix0)
    u16* H0 = (u16*)d_out;
    u16* H1 = H0 + 44040192;
    u16* WeBf = H1;
    u16* W3Bf = H1 + 589824;
    float* attn0 = out + 44040192;
    float* attn1 = attn0 + 802816;
    float* attn2 = attn1 + 802816;

    // ---- prep (2 launches) ----
    mega_prep<<<dim3(1776), 256, 0, stream>>>(W_emb, gat_W, W_out, gat_a, b_emb,
                                              Wt, WeBf, W3Bf, w3ai, w3aj, bfus);
    // stacked prep GEMM writes fused weights DIRECTLY as bf16 K-major:
    // rows 0-767:  C'[n][k] = (We*W1)[k][n]   -> Wt5
    // rows 768+ :  C'[n][k] = (W3*Wout)[k][n] -> Wt6
    gemm_bt<false, false><<<dim3(72), 256, 0, stream>>>(
        Wt + 1 * 589824, Wt + 4 * 589824, WeBf, W3Bf, nullptr, Wt + 5 * 589824);

    dim3 gg(2688);
    // layer 0 (embed fused, fp32 A direct): Wh1 = features @ (We*W1) + be*W1
    gemm_a32<true><<<gg, 256, 0, stream>>>(features, Wt + 5 * 589824, bfus, Wh);
    gat_mix<true, false><<<dim3(4096), 256, 0, stream>>>(Wh, adj, gat_a, attn0, H1,
                                                         nullptr, nullptr, nullptr, nullptr);
    // layer 1: Wh2 = x1 @ W2 ; mix also emits ei3/ej3
    gemm_bt<false, true><<<gg, 256, 0, stream>>>(
        H1, nullptr, Wt + 2 * 589824, nullptr, nullptr, Wh);
    gat_mix<true, true><<<dim3(4096), 256, 0, stream>>>(Wh, adj, gat_a + 1536, attn1, H0,
                                                        w3ai, w3aj, eiG, ejG);
    // layer 2 + out-proj fused: Z = x2 @ (W3*W_out); out = attn2 @ Z + b_out
    gemm_bt<false, true><<<gg, 256, 0, stream>>>(
        H0, nullptr, Wt + 6 * 589824, nullptr, nullptr, Wh);
    gat_out<<<dim3(4096), 256, 0, stream>>>(Wh, adj, eiG, ejG, b_out, attn2, out);
}

// Round 16
// 576.936 us; speedup vs baseline: 1.1488x; 1.1488x over previous
//
#include <hip/hip_runtime.h>

typedef unsigned short u16;
typedef float f32x16 __attribute__((ext_vector_type(16)));
typedef short bf16x8 __attribute__((ext_vector_type(8)));
typedef unsigned short u16x8 __attribute__((ext_vector_type(8)));

#define ND 768
#define KD 768

__device__ __forceinline__ float bf2f(u16 u) {
    union { unsigned i; float f; } v; v.i = ((unsigned)u) << 16; return v.f;
}
__device__ __forceinline__ u16 f2bf(float f) {
    union { float f; unsigned u; } x; x.f = f;
    unsigned r = x.u + 0x7fffu + ((x.u >> 16) & 1u);
    return (u16)(r >> 16);
}
__device__ __forceinline__ void async16(const void* g, void* l) {
    __builtin_amdgcn_global_load_lds((const __attribute__((address_space(1))) void*)g,
                                     (__attribute__((address_space(3))) void*)l, 16, 0, 0);
}

// ---- fused prep: weight transposes + We/W3 casts + vecs + features cast ----
// blocks 0..431:    conv_w for m in {1,2,4} (W1, W2, W_out -> Wt K-major bf16)
// blocks 432..1583: row-major bf16 casts of We (576) and W3 (576)
// blocks 1584..1775: wave-per-d vecs: w3ai/w3aj (W3 rows), bfus (W1 cols, f2bf)
// blocks 1776..5871: features fp32 -> bf16 (grid-stride, 4096 blocks)
__global__ __launch_bounds__(256) void mega_prep(const float* __restrict__ W_emb,
                                                 const float* __restrict__ gat_W,
                                                 const float* __restrict__ W_out,
                                                 const float* __restrict__ gat_a,
                                                 const float* __restrict__ be,
                                                 const float4* __restrict__ features,
                                                 u16* __restrict__ Wt,
                                                 u16* __restrict__ WeBf,
                                                 u16* __restrict__ W3Bf,
                                                 u16* __restrict__ H0,
                                                 float* __restrict__ w3ai,
                                                 float* __restrict__ w3aj,
                                                 float* __restrict__ bfus)
{
    __shared__ float lds[64][65];
    const int blk = blockIdx.x;
    const int tid = threadIdx.x;
    if (blk < 432) {
        const int mi = blk / 144;                 // 0,1,2
        const int mm = (mi == 0) ? 1 : (mi == 1) ? 2 : 4;
        const float* src = (mm == 4) ? W_out : gat_W + (size_t)(mm - 1) * 589824;
        const int r  = blk % 144;
        const int tr = r / 12, tc = r % 12;
        const int c  = tid & 63, w4 = tid >> 6;
        #pragma unroll
        for (int i = 0; i < 16; ++i) {
            int kk = i * 4 + w4;
            lds[kk][c] = src[(size_t)(tr * 64 + kk) * 768 + tc * 64 + c];
        }
        __syncthreads();
        u16* dst = Wt + (size_t)mm * 589824;
        #pragma unroll
        for (int i = 0; i < 16; ++i) {
            int nn = i * 4 + w4;
            dst[(size_t)(tc * 64 + nn) * 768 + tr * 64 + c] = f2bf(lds[c][nn]);
        }
    } else if (blk < 1584) {
        int bi = blk - 432;
        const float4* src;
        u16* dst;
        if (bi < 576) { src = (const float4*)W_emb; dst = WeBf; }
        else          { src = (const float4*)(gat_W + 2 * 589824); dst = W3Bf; bi -= 576; }
        const int i = bi * 256 + tid;             // < 147456
        float4 v = src[i];
        union { u16 s[4]; uint2 u; } o;
        o.s[0] = f2bf(v.x); o.s[1] = f2bf(v.y); o.s[2] = f2bf(v.z); o.s[3] = f2bf(v.w);
        ((uint2*)dst)[i] = o.u;
    } else if (blk < 1776) {
        const int lane = tid & 63;
        const int d = (blk - 1584) * 4 + (tid >> 6);   // < 768
        const float* w3row = gat_W + 2 * 589824 + (size_t)d * 768;
        const float* ga2   = gat_a + 2 * 1536;
        const float* W1    = gat_W;                    // layer 0 weights
        float ai = 0.f, aj = 0.f, bf = 0.f;
        for (int j = lane; j < 768; j += 64) {
            float w = w3row[j];
            ai += w * ga2[j];
            aj += w * ga2[768 + j];
            bf += be[j] * bf2f(f2bf(W1[(size_t)j * 768 + d]));
        }
        #pragma unroll
        for (int off = 32; off; off >>= 1) {
            ai += __shfl_down(ai, off);
            aj += __shfl_down(aj, off);
            bf += __shfl_down(bf, off);
        }
        if (lane == 0) { w3ai[d] = ai; w3aj[d] = aj; bfus[d] = bf; }
    } else {
        for (int i = (blk - 1776) * 256 + tid; i < 11010048; i += 4096 * 256) {
            float4 v = features[i];
            union { u16 s[4]; uint2 u; } o;
            o.s[0] = f2bf(v.x); o.s[1] = f2bf(v.y); o.s[2] = f2bf(v.z); o.s[3] = f2bf(v.w);
            ((uint2*)H0)[i] = o.u;
        }
    }
}

// ---- bf16 GEMM: depth-2 prefetch, 3-buffer circular LDS, counted vmcnt(4) ----
// A2/Bt2: second operand pair selected when tm>=768 (stacked prep GEMM).
template<bool F32OUT, bool SWZ>
__global__ __launch_bounds__(256) void gemm_bt(const u16* __restrict__ A,
                                               const u16* __restrict__ A2,
                                               const u16* __restrict__ Bt,
                                               const u16* __restrict__ Bt2,
                                               const float* __restrict__ bias,
                                               void* __restrict__ Cout)
{
    __shared__ u16 lds3[3][2][4096];   // 48 KB: 3 slots x (A | B) x 128r x 32
    const int tid  = threadIdx.x;
    const int lane = tid & 63;
    const int wvb  = tid & ~63;
    const int wm   = ((tid >> 7) & 1) * 64;
    const int wn   = ((tid >> 6) & 1) * 64;
    const int wg = blockIdx.x;
    const int id = SWZ ? ((wg & 7) * 336 + (wg >> 3)) : wg;
    const int tn = (id % 6) * 128;
    const int tm = (id / 6) * 128;
    const bool hi = (A2 != nullptr) && (tm >= 768);
    const u16* AU  = hi ? A2 : A;
    const u16* BtU = hi ? Bt2 : Bt;
    const int tmA  = hi ? tm - 768 : tm;

    f32x16 acc[2][2] = {};

    const int r31 = lane & 31;
    const int l5  = lane >> 5;
    const int key = (r31 >> 1) & 3;

    const int row0 = tid >> 2;
    const int kc0  = (((tid & 3) ^ ((tid >> 3) & 3)) << 3);
    const u16* aSrc = AU  + (size_t)(tmA + row0) * KD + kc0;
    const u16* bSrc = BtU + (size_t)(tn + row0) * KD + kc0;

    #define STAGE(b, ks_) { const int k0 = (ks_) * 32;                       \
        async16(aSrc + k0,                   &lds3[b][0][wvb * 8]);          \
        async16(aSrc + (size_t)64 * KD + k0, &lds3[b][0][(256 + wvb) * 8]);  \
        async16(bSrc + k0,                   &lds3[b][1][wvb * 8]);          \
        async16(bSrc + (size_t)64 * KD + k0, &lds3[b][1][(256 + wvb) * 8]); }

    STAGE(0, 0);
    STAGE(1, 1);

    #pragma unroll 3
    for (int ks = 0; ks < KD / 32; ++ks) {
        const int cur = ks % 3;
        if (ks < KD / 32 - 1)
            asm volatile("s_waitcnt vmcnt(4)" ::: "memory");  // drain group ks only
        else
            asm volatile("s_waitcnt vmcnt(0)" ::: "memory");  // tail
        __builtin_amdgcn_s_barrier();
        asm volatile("" ::: "memory");
        if (ks + 2 < KD / 32) STAGE((ks + 2) % 3, ks + 2);    // depth-2 prefetch

        const u16* As = lds3[cur][0];
        const u16* Bs = lds3[cur][1];
        bf16x8 af[2][2], bf[2][2];
        #pragma unroll
        for (int fr = 0; fr < 2; ++fr)
            #pragma unroll
            for (int ka = 0; ka < 2; ++ka) {
                int chA = ((ka * 2 + l5) ^ key) << 3;
                af[fr][ka] = *(const bf16x8*)&As[(wm + fr * 32 + r31) * 32 + chA];
                bf[fr][ka] = *(const bf16x8*)&Bs[(wn + fr * 32 + r31) * 32 + chA];
            }
        #pragma unroll
        for (int fr = 0; fr < 2; ++fr)
            #pragma unroll
            for (int fc = 0; fc < 2; ++fc)
                #pragma unroll
                for (int ka = 0; ka < 2; ++ka)
                    acc[fr][fc] = __builtin_amdgcn_mfma_f32_32x32x16_bf16(
                        af[fr][ka], bf[fc][ka], acc[fr][fc], 0, 0, 0);
    }
    #undef STAGE

    // epilogue: 32x32 C/D layout col=lane&31, row=(reg&3)+8*(reg>>2)+4*(lane>>5)
    #pragma unroll
    for (int fc = 0; fc < 2; ++fc) {
        int col = tn + wn + fc * 32 + r31;
        float bv = bias ? bias[col] : 0.0f;
        #pragma unroll
        for (int fr = 0; fr < 2; ++fr) {
            int rowb = tm + wm + fr * 32 + 4 * l5;
            #pragma unroll
            for (int reg = 0; reg < 16; ++reg) {
                int row = rowb + (reg & 3) + 8 * (reg >> 2);
                float v = acc[fr][fc][reg] + bv;
                if (F32OUT)
                    ((float*)Cout)[(size_t)row * ND + col] = v;
                else
                    ((u16*)Cout)[(size_t)row * ND + col] = f2bf(v);
            }
        }
    }
}

// ---- fused GAT attention: ei/ej from staged Wh, softmax, mix, ELU ----
template<bool ELU, bool DOTS>
__global__ __launch_bounds__(256) void gat_mix(const u16* __restrict__ Wh,
                                               const float* __restrict__ adj,
                                               const float* __restrict__ avec,
                                               float* __restrict__ attn_out,
                                               u16* __restrict__ Xout,
                                               const float* __restrict__ w3ai,
                                               const float* __restrict__ w3aj,
                                               float* __restrict__ eiOut,
                                               float* __restrict__ ejOut)
{
    __shared__ u16 wh[14 * 768];
    __shared__ float s_ei[14], s_ej[14];
    __shared__ float s_attn[196];
    __shared__ float s_dots[14][2];
    const int b = blockIdx.x;
    const int tid = threadIdx.x;
    const u16* whb = Wh + (size_t)b * 10752;

    if (DOTS && tid < 28) ((float*)s_dots)[tid] = 0.f;
    for (int c = tid; c < 1344; c += 256)
        ((uint4*)wh)[c] = ((const uint4*)whb)[c];
    __syncthreads();

    if (tid < 224) {
        const int i = tid >> 4, l = tid & 15;
        float ai = 0.f, aj = 0.f;
        #pragma unroll
        for (int c = 0; c < 6; ++c) {
            int d = c * 128 + l * 8;
            u16x8 v  = *(const u16x8*)&wh[i * 768 + d];
            float4 x0 = *(const float4*)&avec[d];
            float4 x1 = *(const float4*)&avec[d + 4];
            float4 y0 = *(const float4*)&avec[768 + d];
            float4 y1 = *(const float4*)&avec[768 + d + 4];
            float w0 = bf2f(v[0]), w1 = bf2f(v[1]), w2 = bf2f(v[2]), w3 = bf2f(v[3]);
            float w4 = bf2f(v[4]), w5 = bf2f(v[5]), w6 = bf2f(v[6]), w7 = bf2f(v[7]);
            ai += w0*x0.x + w1*x0.y + w2*x0.z + w3*x0.w + w4*x1.x + w5*x1.y + w6*x1.z + w7*x1.w;
            aj += w0*y0.x + w1*y0.y + w2*y0.z + w3*y0.w + w4*y1.x + w5*y1.y + w6*y1.z + w7*y1.w;
        }
        #pragma unroll
        for (int off = 8; off; off >>= 1) {
            ai += __shfl_xor(ai, off);
            aj += __shfl_xor(aj, off);
        }
        if (l == 0) { s_ei[i] = ai; s_ej[i] = aj; }
    }
    __syncthreads();

    if (tid < 14) {
        const int i = tid;
        float e[14];
        float mx = -3.0e38f;
        #pragma unroll
        for (int j = 0; j < 14; ++j) {
            float ev = (adj[(size_t)b * 196 + i * 14 + j] > 0.f) ? (s_ei[i] + s_ej[j]) : -1.0e30f;
            e[j] = ev; mx = fmaxf(mx, ev);
        }
        float sum = 0.f;
        #pragma unroll
        for (int j = 0; j < 14; ++j) { float pp = __expf(e[j] - mx); e[j] = pp; sum += pp; }
        float inv = 1.0f / sum;
        #pragma unroll
        for (int j = 0; j < 14; ++j) s_attn[i * 14 + j] = e[j] * inv;
    }
    __syncthreads();

    if (tid < 196) attn_out[(size_t)b * 196 + tid] = s_attn[tid];

    for (int pp = tid; pp < 14 * 48; pp += 256) {
        const int i  = pp / 48;
        const int d0 = (pp % 48) * 16;
        float acc[16] = {};
        #pragma unroll
        for (int j = 0; j < 14; ++j) {
            float aw = s_attn[i * 14 + j];
            u16x8 wv0 = *(const u16x8*)&wh[j * 768 + d0];
            u16x8 wv1 = *(const u16x8*)&wh[j * 768 + d0 + 8];
            #pragma unroll
            for (int qq = 0; qq < 8; ++qq) {
                acc[qq]     += aw * bf2f(wv0[qq]);
                acc[8 + qq] += aw * bf2f(wv1[qq]);
            }
        }
        float pi = 0.f, pj = 0.f;
        union { u16 s[16]; uint4 u[2]; } o;
        #pragma unroll
        for (int qq = 0; qq < 16; ++qq) {
            float v = acc[qq];
            if (ELU && v < 0.f) v = __expf(v) - 1.0f;
            if (DOTS) { pi += v * w3ai[d0 + qq]; pj += v * w3aj[d0 + qq]; }
            o.s[qq] = f2bf(v);
        }
        if (DOTS) {
            atomicAdd(&s_dots[i][0], pi);
            atomicAdd(&s_dots[i][1], pj);
        }
        *(uint4*)&Xout[(size_t)b * 10752 + i * 768 + d0]     = o.u[0];
        *(uint4*)&Xout[(size_t)b * 10752 + i * 768 + d0 + 8] = o.u[1];
    }
    if (DOTS) {
        __syncthreads();
        if (tid < 14) {
            eiOut[(size_t)b * 14 + tid] = s_dots[tid][0];
            ejOut[(size_t)b * 14 + tid] = s_dots[tid][1];
        }
    }
}

// ---- final layer: softmax from precomputed ei3/ej3, out = attn2 @ Z + b_out ----
__global__ __launch_bounds__(256) void gat_out(const u16* __restrict__ Z,
                                               const float* __restrict__ adj,
                                               const float* __restrict__ eiG,
                                               const float* __restrict__ ejG,
                                               const float* __restrict__ b_out,
                                               float* __restrict__ attn_out,
                                               float* __restrict__ outp)
{
    __shared__ u16 wh[14 * 768];
    __shared__ float s_attn[196];
    const int b = blockIdx.x;
    const int tid = threadIdx.x;
    const u16* zb = Z + (size_t)b * 10752;

    for (int c = tid; c < 1344; c += 256)
        ((uint4*)wh)[c] = ((const uint4*)zb)[c];

    if (tid < 14) {
        const int i = tid;
        float ei = eiG[(size_t)b * 14 + i];
        float e[14];
        float mx = -3.0e38f;
        #pragma unroll
        for (int j = 0; j < 14; ++j) {
            float ev = (adj[(size_t)b * 196 + i * 14 + j] > 0.f)
                           ? (ei + ejG[(size_t)b * 14 + j]) : -1.0e30f;
            e[j] = ev; mx = fmaxf(mx, ev);
        }
        float sum = 0.f;
        #pragma unroll
        for (int j = 0; j < 14; ++j) { float pp = __expf(e[j] - mx); e[j] = pp; sum += pp; }
        float inv = 1.0f / sum;
        #pragma unroll
        for (int j = 0; j < 14; ++j) s_attn[i * 14 + j] = e[j] * inv;
    }
    __syncthreads();

    if (tid < 196) attn_out[(size_t)b * 196 + tid] = s_attn[tid];

    for (int pp = tid; pp < 14 * 48; pp += 256) {
        const int i  = pp / 48;
        const int d0 = (pp % 48) * 16;
        float acc[16];
        #pragma unroll
        for (int qq = 0; qq < 16; ++qq) acc[qq] = b_out[d0 + qq];
        #pragma unroll
        for (int j = 0; j < 14; ++j) {
            float aw = s_attn[i * 14 + j];
            u16x8 wv0 = *(const u16x8*)&wh[j * 768 + d0];
            u16x8 wv1 = *(const u16x8*)&wh[j * 768 + d0 + 8];
            #pragma unroll
            for (int qq = 0; qq < 8; ++qq) {
                acc[qq]     += aw * bf2f(wv0[qq]);
                acc[8 + qq] += aw * bf2f(wv1[qq]);
            }
        }
        float* dst = &outp[(size_t)b * 10752 + i * 768 + d0];
        *(float4*)(dst)      = *(float4*)&acc[0];
        *(float4*)(dst + 4)  = *(float4*)&acc[4];
        *(float4*)(dst + 8)  = *(float4*)&acc[8];
        *(float4*)(dst + 12) = *(float4*)&acc[12];
    }
}

extern "C" void kernel_launch(void* const* d_in, const int* in_sizes, int n_in,
                              void* d_out, int out_size, void* d_ws, size_t ws_size,
                              hipStream_t stream)
{
    const float* features = (const float*)d_in[0];
    const float* adj      = (const float*)d_in[1];
    const float* W_emb    = (const float*)d_in[2];
    const float* b_emb    = (const float*)d_in[3];
    const float* gat_W    = (const float*)d_in[4];
    const float* gat_a    = (const float*)d_in[5];
    const float* W_out    = (const float*)d_in[6];
    const float* b_out    = (const float*)d_in[7];
    float* out = (float*)d_out;

    // ws: Wh (bf16 57344x768) | Wt[7] | w3ai | w3aj | bfus | eiG | ejG
    u16* Wh = (u16*)d_ws;
    u16* Wt = Wh + 44040192;
    float* w3ai = (float*)(Wt + 7 * 589824);
    float* w3aj = w3ai + 768;
    float* bfus = w3aj + 768;
    float* eiG  = bfus + 768;
    float* ejG  = eiG + 57344;
    // out-region: ping-pong bf16 halves; WeW3 staging aliases H1 (dead by mix0)
    u16* H0 = (u16*)d_out;
    u16* H1 = H0 + 44040192;
    u16* WeBf = H1;
    u16* W3Bf = H1 + 589824;
    float* attn0 = out + 44040192;
    float* attn1 = attn0 + 802816;
    float* attn2 = attn1 + 802816;

    // ---- prep (2 launches) ----
    mega_prep<<<dim3(5872), 256, 0, stream>>>(W_emb, gat_W, W_out, gat_a, b_emb,
                                              (const float4*)features,
                                              Wt, WeBf, W3Bf, H0, w3ai, w3aj, bfus);
    // stacked prep GEMM writes fused weights DIRECTLY as bf16 K-major:
    // rows 0-767:  C'[n][k] = (We*W1)[k][n]   -> Wt5
    // rows 768+ :  C'[n][k] = (W3*Wout)[k][n] -> Wt6
    gemm_bt<false, false><<<dim3(72), 256, 0, stream>>>(
        Wt + 1 * 589824, Wt + 4 * 589824, WeBf, W3Bf, nullptr, Wt + 5 * 589824);

    dim3 gg(2688);
    // layer 0 (embed fused): Wh1 = features_bf16 @ (We*W1) + be*W1
    gemm_bt<false, true><<<gg, 256, 0, stream>>>(
        H0, nullptr, Wt + 5 * 589824, nullptr, bfus, Wh);
    gat_mix<true, false><<<dim3(4096), 256, 0, stream>>>(Wh, adj, gat_a, attn0, H1,
                                                         nullptr, nullptr, nullptr, nullptr);
    // layer 1: Wh2 = x1 @ W2 ; mix also emits ei3/ej3
    gemm_bt<false, true><<<gg, 256, 0, stream>>>(
        H1, nullptr, Wt + 2 * 589824, nullptr, nullptr, Wh);
    gat_mix<true, true><<<dim3(4096), 256, 0, stream>>>(Wh, adj, gat_a + 1536, attn1, H0,
                                                        w3ai, w3aj, eiG, ejG);
    // layer 2 + out-proj fused: Z = x2 @ (W3*W_out); out = attn2 @ Z + b_out
    gemm_bt<false, true><<<gg, 256, 0, stream>>>(
        H0, nullptr, Wt + 6 * 589824, nullptr, nullptr, Wh);
    gat_out<<<dim3(4096), 256, 0, stream>>>(Wh, adj, eiG, ejG, b_out, attn2, out);
}

// Round 17
// 569.232 us; speedup vs baseline: 1.1643x; 1.0135x over previous
//
#include <hip/hip_runtime.h>

typedef unsigned short u16;
typedef float f32x16 __attribute__((ext_vector_type(16)));
typedef short bf16x8 __attribute__((ext_vector_type(8)));
typedef unsigned short u16x8 __attribute__((ext_vector_type(8)));

#define ND 768
#define KD 768

__device__ __forceinline__ float bf2f(u16 u) {
    union { unsigned i; float f; } v; v.i = ((unsigned)u) << 16; return v.f;
}
__device__ __forceinline__ u16 f2bf(float f) {
    union { float f; unsigned u; } x; x.f = f;
    unsigned r = x.u + 0x7fffu + ((x.u >> 16) & 1u);
    return (u16)(r >> 16);
}
__device__ __forceinline__ void async16(const void* g, void* l) {
    __builtin_amdgcn_global_load_lds((const __attribute__((address_space(1))) void*)g,
                                     (__attribute__((address_space(3))) void*)l, 16, 0, 0);
}

// ---- fused prep: weight transposes + We/W3 casts + vecs + features cast ----
// blocks 0..431:    conv_w for m in {1,2,4} (W1, W2, W_out -> Wt K-major bf16)
// blocks 432..1583: row-major bf16 casts of We (576) and W3 (576)
// blocks 1584..1775: wave-per-d vecs: w3ai/w3aj (W3 rows), bfus (W1 cols, f2bf)
// blocks 1776..5871: features fp32 -> bf16 (grid-stride, 4096 blocks)
__global__ __launch_bounds__(256) void mega_prep(const float* __restrict__ W_emb,
                                                 const float* __restrict__ gat_W,
                                                 const float* __restrict__ W_out,
                                                 const float* __restrict__ gat_a,
                                                 const float* __restrict__ be,
                                                 const float4* __restrict__ features,
                                                 u16* __restrict__ Wt,
                                                 u16* __restrict__ WeBf,
                                                 u16* __restrict__ W3Bf,
                                                 u16* __restrict__ H0,
                                                 float* __restrict__ w3ai,
                                                 float* __restrict__ w3aj,
                                                 float* __restrict__ bfus)
{
    __shared__ float lds[64][65];
    const int blk = blockIdx.x;
    const int tid = threadIdx.x;
    if (blk < 432) {
        const int mi = blk / 144;                 // 0,1,2
        const int mm = (mi == 0) ? 1 : (mi == 1) ? 2 : 4;
        const float* src = (mm == 4) ? W_out : gat_W + (size_t)(mm - 1) * 589824;
        const int r  = blk % 144;
        const int tr = r / 12, tc = r % 12;
        const int c  = tid & 63, w4 = tid >> 6;
        #pragma unroll
        for (int i = 0; i < 16; ++i) {
            int kk = i * 4 + w4;
            lds[kk][c] = src[(size_t)(tr * 64 + kk) * 768 + tc * 64 + c];
        }
        __syncthreads();
        u16* dst = Wt + (size_t)mm * 589824;
        #pragma unroll
        for (int i = 0; i < 16; ++i) {
            int nn = i * 4 + w4;
            dst[(size_t)(tc * 64 + nn) * 768 + tr * 64 + c] = f2bf(lds[c][nn]);
        }
    } else if (blk < 1584) {
        int bi = blk - 432;
        const float4* src;
        u16* dst;
        if (bi < 576) { src = (const float4*)W_emb; dst = WeBf; }
        else          { src = (const float4*)(gat_W + 2 * 589824); dst = W3Bf; bi -= 576; }
        const int i = bi * 256 + tid;             // < 147456
        float4 v = src[i];
        union { u16 s[4]; uint2 u; } o;
        o.s[0] = f2bf(v.x); o.s[1] = f2bf(v.y); o.s[2] = f2bf(v.z); o.s[3] = f2bf(v.w);
        ((uint2*)dst)[i] = o.u;
    } else if (blk < 1776) {
        const int lane = tid & 63;
        const int d = (blk - 1584) * 4 + (tid >> 6);   // < 768
        const float* w3row = gat_W + 2 * 589824 + (size_t)d * 768;
        const float* ga2   = gat_a + 2 * 1536;
        const float* W1    = gat_W;                    // layer 0 weights
        float ai = 0.f, aj = 0.f, bf = 0.f;
        for (int j = lane; j < 768; j += 64) {
            float w = w3row[j];
            ai += w * ga2[j];
            aj += w * ga2[768 + j];
            bf += be[j] * bf2f(f2bf(W1[(size_t)j * 768 + d]));
        }
        #pragma unroll
        for (int off = 32; off; off >>= 1) {
            ai += __shfl_down(ai, off);
            aj += __shfl_down(aj, off);
            bf += __shfl_down(bf, off);
        }
        if (lane == 0) { w3ai[d] = ai; w3aj[d] = aj; bfus[d] = bf; }
    } else {
        for (int i = (blk - 1776) * 256 + tid; i < 11010048; i += 4096 * 256) {
            float4 v = features[i];
            union { u16 s[4]; uint2 u; } o;
            o.s[0] = f2bf(v.x); o.s[1] = f2bf(v.y); o.s[2] = f2bf(v.z); o.s[3] = f2bf(v.w);
            ((uint2*)H0)[i] = o.u;
        }
    }
}

// ---- bf16 GEMM: depth-2 prefetch, 3-buffer circular LDS, counted vmcnt(4) ----
// A2/Bt2: second operand pair selected when tm>=768 (stacked prep GEMM).
template<bool F32OUT, bool SWZ>
__global__ __launch_bounds__(256) void gemm_bt(const u16* __restrict__ A,
                                               const u16* __restrict__ A2,
                                               const u16* __restrict__ Bt,
                                               const u16* __restrict__ Bt2,
                                               const float* __restrict__ bias,
                                               void* __restrict__ Cout)
{
    __shared__ u16 lds3[3][2][4096];   // 48 KB: 3 slots x (A | B) x 128r x 32
    const int tid  = threadIdx.x;
    const int lane = tid & 63;
    const int wvb  = tid & ~63;
    const int wm   = ((tid >> 7) & 1) * 64;
    const int wn   = ((tid >> 6) & 1) * 64;
    const int wg = blockIdx.x;
    const int id = SWZ ? ((wg & 7) * 336 + (wg >> 3)) : wg;
    const int tn = (id % 6) * 128;
    const int tm = (id / 6) * 128;
    const bool hi = (A2 != nullptr) && (tm >= 768);
    const u16* AU  = hi ? A2 : A;
    const u16* BtU = hi ? Bt2 : Bt;
    const int tmA  = hi ? tm - 768 : tm;

    f32x16 acc[2][2] = {};

    const int r31 = lane & 31;
    const int l5  = lane >> 5;
    const int key = (r31 >> 1) & 3;

    const int row0 = tid >> 2;
    const int kc0  = (((tid & 3) ^ ((tid >> 3) & 3)) << 3);
    const u16* aSrc = AU  + (size_t)(tmA + row0) * KD + kc0;
    const u16* bSrc = BtU + (size_t)(tn + row0) * KD + kc0;

    #define STAGE(b, ks_) { const int k0 = (ks_) * 32;                       \
        async16(aSrc + k0,                   &lds3[b][0][wvb * 8]);          \
        async16(aSrc + (size_t)64 * KD + k0, &lds3[b][0][(256 + wvb) * 8]);  \
        async16(bSrc + k0,                   &lds3[b][1][wvb * 8]);          \
        async16(bSrc + (size_t)64 * KD + k0, &lds3[b][1][(256 + wvb) * 8]); }

    STAGE(0, 0);
    STAGE(1, 1);

    #pragma unroll 3
    for (int ks = 0; ks < KD / 32; ++ks) {
        const int cur = ks % 3;
        if (ks < KD / 32 - 1)
            asm volatile("s_waitcnt vmcnt(4)" ::: "memory");  // drain group ks only
        else
            asm volatile("s_waitcnt vmcnt(0)" ::: "memory");  // tail
        __builtin_amdgcn_s_barrier();
        asm volatile("" ::: "memory");
        if (ks + 2 < KD / 32) STAGE((ks + 2) % 3, ks + 2);    // depth-2 prefetch

        const u16* As = lds3[cur][0];
        const u16* Bs = lds3[cur][1];
        bf16x8 af[2][2], bf[2][2];
        #pragma unroll
        for (int fr = 0; fr < 2; ++fr)
            #pragma unroll
            for (int ka = 0; ka < 2; ++ka) {
                int chA = ((ka * 2 + l5) ^ key) << 3;
                af[fr][ka] = *(const bf16x8*)&As[(wm + fr * 32 + r31) * 32 + chA];
                bf[fr][ka] = *(const bf16x8*)&Bs[(wn + fr * 32 + r31) * 32 + chA];
            }
        #pragma unroll
        for (int fr = 0; fr < 2; ++fr)
            #pragma unroll
            for (int fc = 0; fc < 2; ++fc)
                #pragma unroll
                for (int ka = 0; ka < 2; ++ka)
                    acc[fr][fc] = __builtin_amdgcn_mfma_f32_32x32x16_bf16(
                        af[fr][ka], bf[fc][ka], acc[fr][fc], 0, 0, 0);
    }
    #undef STAGE

    // epilogue: 32x32 C/D layout col=lane&31, row=(reg&3)+8*(reg>>2)+4*(lane>>5)
    #pragma unroll
    for (int fc = 0; fc < 2; ++fc) {
        int col = tn + wn + fc * 32 + r31;
        float bv = bias ? bias[col] : 0.0f;
        #pragma unroll
        for (int fr = 0; fr < 2; ++fr) {
            int rowb = tm + wm + fr * 32 + 4 * l5;
            #pragma unroll
            for (int reg = 0; reg < 16; ++reg) {
                int row = rowb + (reg & 3) + 8 * (reg >> 2);
                float v = acc[fr][fc][reg] + bv;
                if (F32OUT)
                    ((float*)Cout)[(size_t)row * ND + col] = v;
                else
                    ((u16*)Cout)[(size_t)row * ND + col] = f2bf(v);
            }
        }
    }
}

// ---- fused GAT attention: ei/ej from staged Wh, softmax, mix, ELU ----
// Wh slice staged via fire-and-forget global_load_lds (gemm STAGE pattern:
// wave-uniform LDS base, per-lane global src, explicit vmcnt(0) drain).
template<bool ELU, bool DOTS>
__global__ __launch_bounds__(256) void gat_mix(const u16* __restrict__ Wh,
                                               const float* __restrict__ adj,
                                               const float* __restrict__ avec,
                                               float* __restrict__ attn_out,
                                               u16* __restrict__ Xout,
                                               const float* __restrict__ w3ai,
                                               const float* __restrict__ w3aj,
                                               float* __restrict__ eiOut,
                                               float* __restrict__ ejOut)
{
    __shared__ u16 wh[14 * 768];
    __shared__ float s_ei[14], s_ej[14];
    __shared__ float s_attn[196];
    __shared__ float s_dots[14][2];
    const int b = blockIdx.x;
    const int tid = threadIdx.x;
    const int wvb = tid & ~63;
    const u16* whb = Wh + (size_t)b * 10752;

    // stage 1344 16B-chunks: 5 full-wave rounds + wave-0 tail (64 chunks)
    #pragma unroll
    for (int k = 0; k < 5; ++k)
        async16(whb + (size_t)(k * 256 + tid) * 8, &wh[(k * 256 + wvb) * 8]);
    if (tid < 64)
        async16(whb + (size_t)(1280 + tid) * 8, &wh[1280 * 8]);
    if (DOTS && tid < 28) ((float*)s_dots)[tid] = 0.f;
    asm volatile("s_waitcnt vmcnt(0)" ::: "memory");
    __syncthreads();

    if (tid < 224) {
        const int i = tid >> 4, l = tid & 15;
        float ai = 0.f, aj = 0.f;
        #pragma unroll
        for (int c = 0; c < 6; ++c) {
            int d = c * 128 + l * 8;
            u16x8 v  = *(const u16x8*)&wh[i * 768 + d];
            float4 x0 = *(const float4*)&avec[d];
            float4 x1 = *(const float4*)&avec[d + 4];
            float4 y0 = *(const float4*)&avec[768 + d];
            float4 y1 = *(const float4*)&avec[768 + d + 4];
            float w0 = bf2f(v[0]), w1 = bf2f(v[1]), w2 = bf2f(v[2]), w3 = bf2f(v[3]);
            float w4 = bf2f(v[4]), w5 = bf2f(v[5]), w6 = bf2f(v[6]), w7 = bf2f(v[7]);
            ai += w0*x0.x + w1*x0.y + w2*x0.z + w3*x0.w + w4*x1.x + w5*x1.y + w6*x1.z + w7*x1.w;
            aj += w0*y0.x + w1*y0.y + w2*y0.z + w3*y0.w + w4*y1.x + w5*y1.y + w6*y1.z + w7*y1.w;
        }
        #pragma unroll
        for (int off = 8; off; off >>= 1) {
            ai += __shfl_xor(ai, off);
            aj += __shfl_xor(aj, off);
        }
        if (l == 0) { s_ei[i] = ai; s_ej[i] = aj; }
    }
    __syncthreads();

    if (tid < 14) {
        const int i = tid;
        float e[14];
        float mx = -3.0e38f;
        #pragma unroll
        for (int j = 0; j < 14; ++j) {
            float ev = (adj[(size_t)b * 196 + i * 14 + j] > 0.f) ? (s_ei[i] + s_ej[j]) : -1.0e30f;
            e[j] = ev; mx = fmaxf(mx, ev);
        }
        float sum = 0.f;
        #pragma unroll
        for (int j = 0; j < 14; ++j) { float pp = __expf(e[j] - mx); e[j] = pp; sum += pp; }
        float inv = 1.0f / sum;
        #pragma unroll
        for (int j = 0; j < 14; ++j) s_attn[i * 14 + j] = e[j] * inv;
    }
    __syncthreads();

    if (tid < 196) attn_out[(size_t)b * 196 + tid] = s_attn[tid];

    for (int pp = tid; pp < 14 * 48; pp += 256) {
        const int i  = pp / 48;
        const int d0 = (pp % 48) * 16;
        float acc[16] = {};
        #pragma unroll
        for (int j = 0; j < 14; ++j) {
            float aw = s_attn[i * 14 + j];
            u16x8 wv0 = *(const u16x8*)&wh[j * 768 + d0];
            u16x8 wv1 = *(const u16x8*)&wh[j * 768 + d0 + 8];
            #pragma unroll
            for (int qq = 0; qq < 8; ++qq) {
                acc[qq]     += aw * bf2f(wv0[qq]);
                acc[8 + qq] += aw * bf2f(wv1[qq]);
            }
        }
        float pi = 0.f, pj = 0.f;
        union { u16 s[16]; uint4 u[2]; } o;
        #pragma unroll
        for (int qq = 0; qq < 16; ++qq) {
            float v = acc[qq];
            if (ELU && v < 0.f) v = __expf(v) - 1.0f;
            if (DOTS) { pi += v * w3ai[d0 + qq]; pj += v * w3aj[d0 + qq]; }
            o.s[qq] = f2bf(v);
        }
        if (DOTS) {
            atomicAdd(&s_dots[i][0], pi);
            atomicAdd(&s_dots[i][1], pj);
        }
        *(uint4*)&Xout[(size_t)b * 10752 + i * 768 + d0]     = o.u[0];
        *(uint4*)&Xout[(size_t)b * 10752 + i * 768 + d0 + 8] = o.u[1];
    }
    if (DOTS) {
        __syncthreads();
        if (tid < 14) {
            eiOut[(size_t)b * 14 + tid] = s_dots[tid][0];
            ejOut[(size_t)b * 14 + tid] = s_dots[tid][1];
        }
    }
}

// ---- final layer: softmax from precomputed ei3/ej3, out = attn2 @ Z + b_out ----
__global__ __launch_bounds__(256) void gat_out(const u16* __restrict__ Z,
                                               const float* __restrict__ adj,
                                               const float* __restrict__ eiG,
                                               const float* __restrict__ ejG,
                                               const float* __restrict__ b_out,
                                               float* __restrict__ attn_out,
                                               float* __restrict__ outp)
{
    __shared__ u16 wh[14 * 768];
    __shared__ float s_attn[196];
    const int b = blockIdx.x;
    const int tid = threadIdx.x;
    const int wvb = tid & ~63;
    const u16* zb = Z + (size_t)b * 10752;

    #pragma unroll
    for (int k = 0; k < 5; ++k)
        async16(zb + (size_t)(k * 256 + tid) * 8, &wh[(k * 256 + wvb) * 8]);
    if (tid < 64)
        async16(zb + (size_t)(1280 + tid) * 8, &wh[1280 * 8]);

    if (tid < 14) {
        const int i = tid;
        float ei = eiG[(size_t)b * 14 + i];
        float e[14];
        float mx = -3.0e38f;
        #pragma unroll
        for (int j = 0; j < 14; ++j) {
            float ev = (adj[(size_t)b * 196 + i * 14 + j] > 0.f)
                           ? (ei + ejG[(size_t)b * 14 + j]) : -1.0e30f;
            e[j] = ev; mx = fmaxf(mx, ev);
        }
        float sum = 0.f;
        #pragma unroll
        for (int j = 0; j < 14; ++j) { float pp = __expf(e[j] - mx); e[j] = pp; sum += pp; }
        float inv = 1.0f / sum;
        #pragma unroll
        for (int j = 0; j < 14; ++j) s_attn[i * 14 + j] = e[j] * inv;
    }
    asm volatile("s_waitcnt vmcnt(0)" ::: "memory");
    __syncthreads();

    if (tid < 196) attn_out[(size_t)b * 196 + tid] = s_attn[tid];

    for (int pp = tid; pp < 14 * 48; pp += 256) {
        const int i  = pp / 48;
        const int d0 = (pp % 48) * 16;
        float acc[16];
        #pragma unroll
        for (int qq = 0; qq < 16; ++qq) acc[qq] = b_out[d0 + qq];
        #pragma unroll
        for (int j = 0; j < 14; ++j) {
            float aw = s_attn[i * 14 + j];
            u16x8 wv0 = *(const u16x8*)&wh[j * 768 + d0];
            u16x8 wv1 = *(const u16x8*)&wh[j * 768 + d0 + 8];
            #pragma unroll
            for (int qq = 0; qq < 8; ++qq) {
                acc[qq]     += aw * bf2f(wv0[qq]);
                acc[8 + qq] += aw * bf2f(wv1[qq]);
            }
        }
        float* dst = &outp[(size_t)b * 10752 + i * 768 + d0];
        *(float4*)(dst)      = *(float4*)&acc[0];
        *(float4*)(dst + 4)  = *(float4*)&acc[4];
        *(float4*)(dst + 8)  = *(float4*)&acc[8];
        *(float4*)(dst + 12) = *(float4*)&acc[12];
    }
}

extern "C" void kernel_launch(void* const* d_in, const int* in_sizes, int n_in,
                              void* d_out, int out_size, void* d_ws, size_t ws_size,
                              hipStream_t stream)
{
    const float* features = (const float*)d_in[0];
    const float* adj      = (const float*)d_in[1];
    const float* W_emb    = (const float*)d_in[2];
    const float* b_emb    = (const float*)d_in[3];
    const float* gat_W    = (const float*)d_in[4];
    const float* gat_a    = (const float*)d_in[5];
    const float* W_out    = (const float*)d_in[6];
    const float* b_out    = (const float*)d_in[7];
    float* out = (float*)d_out;

    // ws: Wh (bf16 57344x768) | Wt[7] | w3ai | w3aj | bfus | eiG | ejG
    u16* Wh = (u16*)d_ws;
    u16* Wt = Wh + 44040192;
    float* w3ai = (float*)(Wt + 7 * 589824);
    float* w3aj = w3ai + 768;
    float* bfus = w3aj + 768;
    float* eiG  = bfus + 768;
    float* ejG  = eiG + 57344;
    // out-region: ping-pong bf16 halves; WeW3 staging aliases H1 (dead by mix0)
    u16* H0 = (u16*)d_out;
    u16* H1 = H0 + 44040192;
    u16* WeBf = H1;
    u16* W3Bf = H1 + 589824;
    float* attn0 = out + 44040192;
    float* attn1 = attn0 + 802816;
    float* attn2 = attn1 + 802816;

    // ---- prep (2 launches) ----
    mega_prep<<<dim3(5872), 256, 0, stream>>>(W_emb, gat_W, W_out, gat_a, b_emb,
                                              (const float4*)features,
                                              Wt, WeBf, W3Bf, H0, w3ai, w3aj, bfus);
    // stacked prep GEMM writes fused weights DIRECTLY as bf16 K-major:
    // rows 0-767:  C'[n][k] = (We*W1)[k][n]   -> Wt5
    // rows 768+ :  C'[n][k] = (W3*Wout)[k][n] -> Wt6
    gemm_bt<false, false><<<dim3(72), 256, 0, stream>>>(
        Wt + 1 * 589824, Wt + 4 * 589824, WeBf, W3Bf, nullptr, Wt + 5 * 589824);

    dim3 gg(2688);
    // layer 0 (embed fused): Wh1 = features_bf16 @ (We*W1) + be*W1
    gemm_bt<false, true><<<gg, 256, 0, stream>>>(
        H0, nullptr, Wt + 5 * 589824, nullptr, bfus, Wh);
    gat_mix<true, false><<<dim3(4096), 256, 0, stream>>>(Wh, adj, gat_a, attn0, H1,
                                                         nullptr, nullptr, nullptr, nullptr);
    // layer 1: Wh2 = x1 @ W2 ; mix also emits ei3/ej3
    gemm_bt<false, true><<<gg, 256, 0, stream>>>(
        H1, nullptr, Wt + 2 * 589824, nullptr, nullptr, Wh);
    gat_mix<true, true><<<dim3(4096), 256, 0, stream>>>(Wh, adj, gat_a + 1536, attn1, H0,
                                                        w3ai, w3aj, eiG, ejG);
    // layer 2 + out-proj fused: Z = x2 @ (W3*W_out); out = attn2 @ Z + b_out
    gemm_bt<false, true><<<gg, 256, 0, stream>>>(
        H0, nullptr, Wt + 6 * 589824, nullptr, nullptr, Wh);
    gat_out<<<dim3(4096), 256, 0, stream>>>(Wh, adj, eiG, ejG, b_out, attn2, out);
}